// Round 1
// baseline (146.645 us; speedup 1.0000x reference)
//
#include <hip/hip_runtime.h>
#include <hip/hip_bf16.h>

typedef __attribute__((ext_vector_type(4))) float f32x4;
typedef __attribute__((ext_vector_type(4))) int   i32x4;
typedef __attribute__((ext_vector_type(8))) short s16x8;

#define KCOLS 256
#define KC 32

__device__ __forceinline__ unsigned int f2bf(float v){
    // round-to-nearest-even fp32 -> bf16 (inputs are finite, in [0,1))
    union { float f; unsigned int u; } x; x.f = v;
    return (x.u + 0x7fffu + ((x.u >> 16) & 1u)) >> 16;
}

// ---------------------------------------------------------------------------
// K1: streaming GEMM C = c0^T * c1 (bf16 MFMA, fp32 acc) + column sums/sqsums.
// Each block: full 256x256 C partial over a grid-strided set of 32-row chunks.
// LDS layout per matrix: [col][32] bf16 (64B col stride), octet-swizzled:
//   idx_ushort(col,k) = col*32 + (((k>>3) ^ ((col>>2)&3)) << 3) + (k&7)
// -> ds_read_b128 fragment reads conflict-free, ds_write_b128 ~2-way.
// ---------------------------------------------------------------------------
__global__ __launch_bounds__(512, 2) void k1_gemm(
        const float* __restrict__ c0, const float* __restrict__ c1,
        float* __restrict__ Pc, float* __restrict__ Ps, int nrows)
{
    const int tid = threadIdx.x;
    const int w   = tid >> 6;          // wave 0..7
    const int l   = tid & 63;          // lane
    const int mat = w >> 2;            // staging: which matrix this wave stages
    const int oct = w & 3;             // staging: row-octet (8 rows) within chunk
    const int wr  = w >> 2;            // compute: C row-half (128 rows)
    const int wc  = w & 3;             // compute: C col-quarter (64 cols)
    const int b   = blockIdx.x;
    const int B   = gridDim.x;
    const int nchunk = (nrows + KC - 1) / KC;

    __shared__ __align__(16) unsigned short lds[2][2][8192]; // [dbuf][matrix][col*32+swz]
    __shared__ float sred[2][4][256];
    __shared__ float qred[2][4][256];

    const float* src = mat ? c1 : c0;
    const int colbase = l << 2;                 // this lane stages cols 4l..4l+3
    const int wsw = ((oct ^ (l & 3)) << 3);     // write swizzle (col>>2)&3 == l&3

    // Precompute fragment read offsets (ushort units) within one matrix buffer.
    int idxA[8], idxB[4];
#pragma unroll
    for (int mt = 0; mt < 8; ++mt){
        int col = wr*128 + mt*16 + (l & 15);
        idxA[mt] = col*32 + ((((l >> 4)) ^ ((col >> 2) & 3)) << 3);
    }
#pragma unroll
    for (int nt = 0; nt < 4; ++nt){
        int col = wc*64 + nt*16 + (l & 15);
        idxB[nt] = col*32 + ((((l >> 4)) ^ ((col >> 2) & 3)) << 3);
    }

    f32x4 acc[8][4];
    const f32x4 zf = {0.f, 0.f, 0.f, 0.f};
#pragma unroll
    for (int i = 0; i < 8; ++i)
#pragma unroll
        for (int j = 0; j < 4; ++j) acc[i][j] = zf;

    float sum[4] = {0.f,0.f,0.f,0.f};
    float sq [4] = {0.f,0.f,0.f,0.f};

    f32x4 f[8];
    int c = b;
    if (c < nchunk){
        int rbase = c*KC + oct*8;
#pragma unroll
        for (int rr = 0; rr < 8; ++rr){
            int row = rbase + rr;
            f[rr] = (row < nrows) ? *(const f32x4*)(src + (size_t)row*KCOLS + colbase) : zf;
        }
    }

    int p = 0;
    while (c < nchunk){
        // ---- pack chunk c -> LDS buf[p], accumulate column sums/sqsums ----
        unsigned short* dst = &lds[p][mat][0];
#pragma unroll
        for (int cc = 0; cc < 4; ++cc){
            float v0=f[0][cc], v1=f[1][cc], v2=f[2][cc], v3=f[3][cc];
            float v4=f[4][cc], v5=f[5][cc], v6=f[6][cc], v7=f[7][cc];
            sum[cc] += ((v0+v1)+(v2+v3)) + ((v4+v5)+(v6+v7));
            sq [cc] += ((v0*v0+v1*v1)+(v2*v2+v3*v3)) + ((v4*v4+v5*v5)+(v6*v6+v7*v7));
            i32x4 pk;
            pk.x = (int)(f2bf(v0) | (f2bf(v1) << 16));
            pk.y = (int)(f2bf(v2) | (f2bf(v3) << 16));
            pk.z = (int)(f2bf(v4) | (f2bf(v5) << 16));
            pk.w = (int)(f2bf(v6) | (f2bf(v7) << 16));
            *(i32x4*)&dst[(colbase + cc)*32 + wsw] = pk;
        }
        __syncthreads();

        // ---- issue next chunk's global loads (latency hidden under MFMA) ----
        int cn = c + B;
        if (cn < nchunk){
            int rbase = cn*KC + oct*8;
#pragma unroll
            for (int rr = 0; rr < 8; ++rr){
                int row = rbase + rr;
                f[rr] = (row < nrows) ? *(const f32x4*)(src + (size_t)row*KCOLS + colbase) : zf;
            }
        }

        // ---- MFMA over buf[p]: 8 m-tiles x 4 n-tiles, K=32 ----
        const unsigned short* bufA = &lds[p][0][0];
        const unsigned short* bufB = &lds[p][1][0];
        s16x8 bfr[4];
#pragma unroll
        for (int nt = 0; nt < 4; ++nt) bfr[nt] = *(const s16x8*)&bufB[idxB[nt]];
#pragma unroll
        for (int mt = 0; mt < 8; ++mt){
            s16x8 afr = *(const s16x8*)&bufA[idxA[mt]];
#pragma unroll
            for (int nt = 0; nt < 4; ++nt)
                acc[mt][nt] = __builtin_amdgcn_mfma_f32_16x16x32_bf16(
                                  afr, bfr[nt], acc[mt][nt], 0, 0, 0);
        }
        p ^= 1;
        c  = cn;
        // single barrier per chunk is sufficient: next pack targets buf[p^1];
        // buf[p] is rewritten only 2 iterations later, past the next barrier.
    }

    // ---- write 256x256 fp32 C partial ----
    float* Pb = Pc + (size_t)b * 65536;
#pragma unroll
    for (int mt = 0; mt < 8; ++mt)
#pragma unroll
        for (int nt = 0; nt < 4; ++nt)
#pragma unroll
            for (int r = 0; r < 4; ++r){
                int row = wr*128 + mt*16 + (l >> 4)*4 + r;  // C/D: row=(l>>4)*4+reg
                int cl  = wc*64  + nt*16 + (l & 15);        //      col=l&15
                Pb[row*256 + cl] = acc[mt][nt][r];
            }

    // ---- reduce per-block column sums across the 4 staging octets ----
#pragma unroll
    for (int cc = 0; cc < 4; ++cc){
        sred[mat][oct][colbase + cc] = sum[cc];
        qred[mat][oct][colbase + cc] = sq[cc];
    }
    __syncthreads();
    {
        int m2 = tid >> 8, cl = tid & 255;
        float s = sred[m2][0][cl] + sred[m2][1][cl] + sred[m2][2][cl] + sred[m2][3][cl];
        float q = qred[m2][0][cl] + qred[m2][1][cl] + qred[m2][2][cl] + qred[m2][3][cl];
        Ps[(size_t)b*1024 + m2*512 + cl]       = s;
        Ps[(size_t)b*1024 + m2*512 + 256 + cl] = q;
    }
}

// ---------------------------------------------------------------------------
// K2: reduce per-block sum partials -> finals[1024] = {s0,q0,s1,q1} (fp64 acc)
// ---------------------------------------------------------------------------
__global__ __launch_bounds__(256) void k2_sum(const float* __restrict__ Ps,
                                              float* __restrict__ fin, int B)
{
    int tid = threadIdx.x;
    int u   = blockIdx.x*64 + (tid & 63);
    int sub = tid >> 6;
    double a = 0.0;
    for (int b = sub; b < B; b += 4) a += Ps[(size_t)b*1024 + u];
    __shared__ double sc2[4][64];
    sc2[sub][tid & 63] = a;
    __syncthreads();
    if (sub == 0)
        fin[u] = (float)(sc2[0][tid] + sc2[1][tid] + sc2[2][tid] + sc2[3][tid]);
}

// ---------------------------------------------------------------------------
// K3: per C-row j: reduce C partials, cosine, row softmax, t_j = log(diag+eps)
// ---------------------------------------------------------------------------
__global__ __launch_bounds__(512) void k3_rows(const float* __restrict__ Pc,
        const float* __restrict__ fin, float* __restrict__ tout, int B)
{
    const int j   = blockIdx.x;
    const int tid = threadIdx.x;
    const int l   = tid & 255;
    const int h   = tid >> 8;

    __shared__ float part[2][256];
    __shared__ float cosS[256];
    __shared__ float wred[8];

    double a = 0.0;
    int b0 = h ? (B >> 1) : 0;
    int b1 = h ? B        : (B >> 1);
    for (int b = b0; b < b1; ++b)
        a += Pc[(size_t)b*65536 + j*256 + l];
    part[h][l] = (float)a;
    __syncthreads();

    if (h == 0){
        float Cjl = part[0][l] + part[1][l];
        float d0 = fin[j]       + 1e-8f, q0 = fin[256 + j];
        float d1 = fin[512 + l] + 1e-8f, q1 = fin[768 + l];
        float rs0 = rsqrtf(fmaxf(q0 / (d0*d0), 1e-12f));
        float rs1 = rsqrtf(fmaxf(q1 / (d1*d1), 1e-12f));
        cosS[l] = Cjl * (rs0 / d0) * (rs1 / d1);
    }
    __syncthreads();

    float v  = (tid < 256) ? cosS[tid] : -3.0e38f;
    float mx = v;
#pragma unroll
    for (int o = 32; o >= 1; o >>= 1) mx = fmaxf(mx, __shfl_xor(mx, o));
    if ((tid & 63) == 0) wred[tid >> 6] = mx;
    __syncthreads();
    mx = wred[0];
#pragma unroll
    for (int i = 1; i < 8; ++i) mx = fmaxf(mx, wred[i]);
    __syncthreads();   // all reads of wred(max) done before reuse

    float e = (tid < 256) ? expf(cosS[tid] - mx) : 0.0f;
    float s = e;
#pragma unroll
    for (int o = 32; o >= 1; o >>= 1) s += __shfl_xor(s, o);
    if ((tid & 63) == 0) wred[tid >> 6] = s;
    __syncthreads();
    float S = ((wred[0]+wred[1])+(wred[2]+wred[3])) + ((wred[4]+wred[5])+(wred[6]+wred[7]));

    if (tid == j){
        float dg = expf(cosS[j] - mx) / S;
        tout[j] = logf(dg + 1e-8f);
    }
}

// ---------------------------------------------------------------------------
// K4: finalize — cls loss + fp64 entropy terms -> d_out[0], d_out[1]
// ---------------------------------------------------------------------------
__global__ __launch_bounds__(256) void k4_fin(const float* __restrict__ fin,
        const float* __restrict__ tout, const int* __restrict__ kptr,
        float* __restrict__ out)
{
    const int tid = threadIdx.x;  // 256 threads
    __shared__ double sc[4];
    auto bsum = [&](double v) -> double {
#pragma unroll
        for (int o = 32; o >= 1; o >>= 1) v += __shfl_xor(v, o);
        if ((tid & 63) == 0) sc[tid >> 6] = v;
        __syncthreads();
        double r = sc[0] + sc[1] + sc[2] + sc[3];
        __syncthreads();
        return r;
    };

    double s0 = fin[tid], s1 = fin[512 + tid];
    double S0 = bsum(s0), S1 = bsum(s1);
    double p0 = s0 / S0, p1 = s1 / S1;
    double T0 = bsum(p0 * log(p0));
    double T1 = bsum(p1 * log(p1));
    double Tc = bsum((double)tout[tid]);

    if (tid == 0){
        double lk = log((double)(*kptr));
        out[0] = (float)(-(Tc / 256.0));
        out[1] = (float)((T0 + lk) + (T1 + lk));
    }
}

extern "C" void kernel_launch(void* const* d_in, const int* in_sizes, int n_in,
                              void* d_out, int out_size, void* d_ws, size_t ws_size,
                              hipStream_t stream)
{
    const float* c0  = (const float*)d_in[0];
    const float* c1  = (const float*)d_in[1];
    const int*  kptr = (const int*)d_in[2];
    float* out = (float*)d_out;
    int nrows = in_sizes[0] / KCOLS;

    // workspace budget: B*(65536 + 1024) + 1024 (finals) + 256 (row terms) floats
    int B = 256;
    size_t need = ((size_t)B*66560 + 1280) * sizeof(float);
    if (need > ws_size){
        long cap = (long)(ws_size / sizeof(float)) - 1280;
        long bb  = cap / 66560;
        B = (int)(bb < 1 ? 1 : (bb > 256 ? 256 : bb));
    }
    float* Pc  = (float*)d_ws;                 // B * 65536
    float* Ps  = Pc + (size_t)B * 65536;       // B * 1024
    float* fin = Ps + (size_t)B * 1024;        // 1024
    float* tv  = fin + 1024;                   // 256

    hipLaunchKernelGGL(k1_gemm, dim3(B),   dim3(512), 0, stream, c0, c1, Pc, Ps, nrows);
    hipLaunchKernelGGL(k2_sum,  dim3(16),  dim3(256), 0, stream, Ps, fin, B);
    hipLaunchKernelGGL(k3_rows, dim3(256), dim3(512), 0, stream, Pc, fin, tv, B);
    hipLaunchKernelGGL(k4_fin,  dim3(1),   dim3(256), 0, stream, fin, tv, kptr, out);
}

// Round 2
// 144.776 us; speedup vs baseline: 1.0129x; 1.0129x over previous
//
#include <hip/hip_runtime.h>
#include <hip/hip_bf16.h>

typedef __attribute__((ext_vector_type(4))) float f32x4;
typedef __attribute__((ext_vector_type(4))) int   i32x4;
typedef __attribute__((ext_vector_type(8))) short s16x8;

#define KCOLS 256
#define KC 32

// ushort index of (col, k) within one 8192-ushort matrix buffer.
// Layout: col-pairs own 128B rows of 8 16B granules; granule for (col&1,koct)
// is XOR-swizzled by (col>>2)&7 -> both ds_write_b128 (granule spread by l&7)
// and frag ds_read_b128 (spread by (col>>2)&7) are 2-way max = conflict-free.
__device__ __forceinline__ int swz_idx(int col, int koct){
    return ((col >> 1) << 6) + ((((((col & 1) << 2) | koct)) ^ ((col >> 2) & 7)) << 3);
}

__device__ __forceinline__ int cvt2(float lo, float hi){
    int r;
    asm("v_cvt_pk_bf16_f32 %0, %1, %2" : "=v"(r) : "v"(lo), "v"(hi));
    return r;
}

__device__ __forceinline__ void block_barrier(){
    // ds_writes visible to other waves, then barrier WITHOUT vmcnt drain:
    // in-flight global prefetch loads survive into the MFMA phase.
    asm volatile("s_waitcnt lgkmcnt(0)" ::: "memory");
    __builtin_amdgcn_sched_barrier(0);
    __builtin_amdgcn_s_barrier();
    __builtin_amdgcn_sched_barrier(0);
    asm volatile("" ::: "memory");
}

// ---------------------------------------------------------------------------
// K1: streaming GEMM C = c0^T * c1 (bf16 MFMA, fp32 acc) + column sums/sqsums.
// ---------------------------------------------------------------------------
__global__ __launch_bounds__(512, 2) void k1_gemm(
        const float* __restrict__ c0, const float* __restrict__ c1,
        float* __restrict__ Pc, float* __restrict__ Ps, int nrows)
{
    const int tid = threadIdx.x;
    const int w   = tid >> 6;          // wave 0..7
    const int l   = tid & 63;          // lane
    const int mat = w >> 2;            // staging: which matrix this wave stages
    const int oct = w & 3;             // staging: row-octet (8 rows) -> k-octet
    const int wr  = w >> 2;            // compute: C row-half (128 rows)
    const int wc  = w & 3;             // compute: C col-quarter (64 cols)
    const int b   = blockIdx.x;
    const int B   = gridDim.x;
    const int nchunk = (nrows + KC - 1) / KC;

    __shared__ __align__(16) unsigned short lds[2][2][8192]; // [dbuf][matrix]
    __shared__ float sred[2][4][256];
    __shared__ float qred[2][4][256];

    const float* src = mat ? c1 : c0;
    const int colbase = l << 2;                 // this lane stages cols 4l..4l+3

    // fragment read offsets (ushort units) within one matrix buffer
    int idxA[8], idxB[4];
#pragma unroll
    for (int mt = 0; mt < 8; ++mt)
        idxA[mt] = swz_idx(wr*128 + mt*16 + (l & 15), l >> 4);
#pragma unroll
    for (int nt = 0; nt < 4; ++nt)
        idxB[nt] = swz_idx(wc*64 + nt*16 + (l & 15), l >> 4);

    // pack write offsets for cc=0..3 (col = 4l+cc, koct = oct)
    int widx[4];
#pragma unroll
    for (int cc = 0; cc < 4; ++cc)
        widx[cc] = (((l << 1) + (cc >> 1)) << 6) +
                   ((((((cc & 1) << 2) | oct)) ^ (l & 7)) << 3);

    f32x4 acc[8][4];
    const f32x4 zf = {0.f, 0.f, 0.f, 0.f};
#pragma unroll
    for (int i = 0; i < 8; ++i)
#pragma unroll
        for (int j = 0; j < 4; ++j) acc[i][j] = zf;

    float sum[4] = {0.f,0.f,0.f,0.f};
    float sq [4] = {0.f,0.f,0.f,0.f};

    f32x4 f[8];
    auto LOAD = [&](int c){
        int rbase = c*KC + oct*8;
        if (rbase + 8 <= nrows){
#pragma unroll
            for (int rr = 0; rr < 8; ++rr)
                f[rr] = *(const f32x4*)(src + (size_t)(rbase+rr)*KCOLS + colbase);
        } else {
#pragma unroll
            for (int rr = 0; rr < 8; ++rr){
                int row = rbase + rr;
                f[rr] = (row < nrows) ? *(const f32x4*)(src + (size_t)row*KCOLS + colbase) : zf;
            }
        }
    };

    int c = b;
    if (c < nchunk) LOAD(c);
    int p = 0;
    while (c < nchunk){
        // ---- pack chunk c -> LDS buf[p]; accumulate column sums/sqsums ----
        unsigned short* dst = &lds[p][mat][0];
#pragma unroll
        for (int cc = 0; cc < 4; ++cc){
            float v0=f[0][cc], v1=f[1][cc], v2=f[2][cc], v3=f[3][cc];
            float v4=f[4][cc], v5=f[5][cc], v6=f[6][cc], v7=f[7][cc];
            sum[cc] += ((v0+v1)+(v2+v3)) + ((v4+v5)+(v6+v7));
            sq [cc] += ((v0*v0+v1*v1)+(v2*v2+v3*v3)) + ((v4*v4+v5*v5)+(v6*v6+v7*v7));
            i32x4 pk;
            pk.x = cvt2(v0, v1);
            pk.y = cvt2(v2, v3);
            pk.z = cvt2(v4, v5);
            pk.w = cvt2(v6, v7);
            *(i32x4*)&dst[widx[cc]] = pk;
        }

        // ---- issue next chunk's loads; they stay in flight across barrier ----
        int cn = c + B;
        if (cn < nchunk) LOAD(cn);

        block_barrier();

        // ---- MFMA over buf[p]: 8 m-tiles x 4 n-tiles, K=32 ----
        const unsigned short* bufA = &lds[p][0][0];
        const unsigned short* bufB = &lds[p][1][0];
        s16x8 bfr[4];
#pragma unroll
        for (int nt = 0; nt < 4; ++nt) bfr[nt] = *(const s16x8*)&bufB[idxB[nt]];
#pragma unroll
        for (int mt = 0; mt < 8; ++mt){
            s16x8 afr = *(const s16x8*)&bufA[idxA[mt]];
#pragma unroll
            for (int nt = 0; nt < 4; ++nt)
                acc[mt][nt] = __builtin_amdgcn_mfma_f32_16x16x32_bf16(
                                  afr, bfr[nt], acc[mt][nt], 0, 0, 0);
        }
        p ^= 1;
        c  = cn;
        // one barrier per chunk: buf[p] is rewritten 2 iterations later, and
        // each wave's ds_reads are lgkm-drained before it passes the barrier.
    }

    // ---- write 256x256 fp32 C partial ----
    float* Pb = Pc + (size_t)b * 65536;
#pragma unroll
    for (int mt = 0; mt < 8; ++mt)
#pragma unroll
        for (int nt = 0; nt < 4; ++nt)
#pragma unroll
            for (int r = 0; r < 4; ++r){
                int row = wr*128 + mt*16 + (l >> 4)*4 + r;  // C/D: row=(l>>4)*4+reg
                int cl  = wc*64  + nt*16 + (l & 15);        //      col=l&15
                Pb[row*256 + cl] = acc[mt][nt][r];
            }

    // ---- reduce per-block column sums across the 4 staging octets ----
#pragma unroll
    for (int cc = 0; cc < 4; ++cc){
        sred[mat][oct][colbase + cc] = sum[cc];
        qred[mat][oct][colbase + cc] = sq[cc];
    }
    __syncthreads();
    {
        int m2 = tid >> 8, cl = tid & 255;
        float s = sred[m2][0][cl] + sred[m2][1][cl] + sred[m2][2][cl] + sred[m2][3][cl];
        float q = qred[m2][0][cl] + qred[m2][1][cl] + qred[m2][2][cl] + qred[m2][3][cl];
        Ps[(size_t)b*1024 + m2*512 + cl]       = s;
        Ps[(size_t)b*1024 + m2*512 + 256 + cl] = q;
    }
}

// ---------------------------------------------------------------------------
// K2: reduce per-block sum partials -> finals[1024] = {s0,q0,s1,q1} (fp64 acc)
// ---------------------------------------------------------------------------
__global__ __launch_bounds__(256) void k2_sum(const float* __restrict__ Ps,
                                              float* __restrict__ fin, int B)
{
    int tid = threadIdx.x;
    int u   = blockIdx.x*64 + (tid & 63);
    int sub = tid >> 6;
    double a = 0.0;
    for (int b = sub; b < B; b += 4) a += Ps[(size_t)b*1024 + u];
    __shared__ double sc2[4][64];
    sc2[sub][tid & 63] = a;
    __syncthreads();
    if (sub == 0)
        fin[u] = (float)(sc2[0][tid] + sc2[1][tid] + sc2[2][tid] + sc2[3][tid]);
}

// ---------------------------------------------------------------------------
// K3: per C-row j: reduce C partials, cosine, row softmax, t_j = log(diag+eps)
// ---------------------------------------------------------------------------
__global__ __launch_bounds__(512) void k3_rows(const float* __restrict__ Pc,
        const float* __restrict__ fin, float* __restrict__ tout, int B)
{
    const int j   = blockIdx.x;
    const int tid = threadIdx.x;
    const int l   = tid & 255;
    const int h   = tid >> 8;

    __shared__ float part[2][256];
    __shared__ float cosS[256];
    __shared__ float wred[8];

    double a = 0.0;
    int b0 = h ? (B >> 1) : 0;
    int b1 = h ? B        : (B >> 1);
    for (int b = b0; b < b1; ++b)
        a += Pc[(size_t)b*65536 + j*256 + l];
    part[h][l] = (float)a;
    __syncthreads();

    if (h == 0){
        float Cjl = part[0][l] + part[1][l];
        float d0 = fin[j]       + 1e-8f, q0 = fin[256 + j];
        float d1 = fin[512 + l] + 1e-8f, q1 = fin[768 + l];
        float rs0 = rsqrtf(fmaxf(q0 / (d0*d0), 1e-12f));
        float rs1 = rsqrtf(fmaxf(q1 / (d1*d1), 1e-12f));
        cosS[l] = Cjl * (rs0 / d0) * (rs1 / d1);
    }
    __syncthreads();

    float v  = (tid < 256) ? cosS[tid] : -3.0e38f;
    float mx = v;
#pragma unroll
    for (int o = 32; o >= 1; o >>= 1) mx = fmaxf(mx, __shfl_xor(mx, o));
    if ((tid & 63) == 0) wred[tid >> 6] = mx;
    __syncthreads();
    mx = wred[0];
#pragma unroll
    for (int i = 1; i < 8; ++i) mx = fmaxf(mx, wred[i]);
    __syncthreads();   // all reads of wred(max) done before reuse

    float e = (tid < 256) ? expf(cosS[tid] - mx) : 0.0f;
    float s = e;
#pragma unroll
    for (int o = 32; o >= 1; o >>= 1) s += __shfl_xor(s, o);
    if ((tid & 63) == 0) wred[tid >> 6] = s;
    __syncthreads();
    float S = ((wred[0]+wred[1])+(wred[2]+wred[3])) + ((wred[4]+wred[5])+(wred[6]+wred[7]));

    if (tid == j){
        float dg = expf(cosS[j] - mx) / S;
        tout[j] = logf(dg + 1e-8f);
    }
}

// ---------------------------------------------------------------------------
// K4: finalize — cls loss + fp64 entropy terms -> d_out[0], d_out[1]
// ---------------------------------------------------------------------------
__global__ __launch_bounds__(256) void k4_fin(const float* __restrict__ fin,
        const float* __restrict__ tout, const int* __restrict__ kptr,
        float* __restrict__ out)
{
    const int tid = threadIdx.x;  // 256 threads
    __shared__ double sc[4];
    auto bsum = [&](double v) -> double {
#pragma unroll
        for (int o = 32; o >= 1; o >>= 1) v += __shfl_xor(v, o);
        if ((tid & 63) == 0) sc[tid >> 6] = v;
        __syncthreads();
        double r = sc[0] + sc[1] + sc[2] + sc[3];
        __syncthreads();
        return r;
    };

    double s0 = fin[tid], s1 = fin[512 + tid];
    double S0 = bsum(s0), S1 = bsum(s1);
    double p0 = s0 / S0, p1 = s1 / S1;
    double T0 = bsum(p0 * log(p0));
    double T1 = bsum(p1 * log(p1));
    double Tc = bsum((double)tout[tid]);

    if (tid == 0){
        double lk = log((double)(*kptr));
        out[0] = (float)(-(Tc / 256.0));
        out[1] = (float)((T0 + lk) + (T1 + lk));
    }
}

extern "C" void kernel_launch(void* const* d_in, const int* in_sizes, int n_in,
                              void* d_out, int out_size, void* d_ws, size_t ws_size,
                              hipStream_t stream)
{
    const float* c0  = (const float*)d_in[0];
    const float* c1  = (const float*)d_in[1];
    const int*  kptr = (const int*)d_in[2];
    float* out = (float*)d_out;
    int nrows = in_sizes[0] / KCOLS;

    // B=250: 6250 chunks / 250 = exactly 25 iterations per block (no tail imbalance)
    int B = 250;
    size_t need = ((size_t)B*66560 + 1280) * sizeof(float);
    if (need > ws_size){
        long cap = (long)(ws_size / sizeof(float)) - 1280;
        long bb  = cap / 66560;
        B = (int)(bb < 1 ? 1 : (bb > 250 ? 250 : bb));
    }
    float* Pc  = (float*)d_ws;                 // B * 65536
    float* Ps  = Pc + (size_t)B * 65536;       // B * 1024
    float* fin = Ps + (size_t)B * 1024;        // 1024
    float* tv  = fin + 1024;                   // 256

    hipLaunchKernelGGL(k1_gemm, dim3(B),   dim3(512), 0, stream, c0, c1, Pc, Ps, nrows);
    hipLaunchKernelGGL(k2_sum,  dim3(16),  dim3(256), 0, stream, Ps, fin, B);
    hipLaunchKernelGGL(k3_rows, dim3(256), dim3(512), 0, stream, Pc, fin, tv, B);
    hipLaunchKernelGGL(k4_fin,  dim3(1),   dim3(256), 0, stream, fin, tv, kptr, out);
}

// Round 3
// 141.386 us; speedup vs baseline: 1.0372x; 1.0240x over previous
//
#include <hip/hip_runtime.h>
#include <hip/hip_bf16.h>

typedef __attribute__((ext_vector_type(4))) float f32x4;
typedef __attribute__((ext_vector_type(2))) int   i32x2;
typedef __attribute__((ext_vector_type(4))) int   i32x4;
typedef __attribute__((ext_vector_type(8))) short s16x8;

#define KCOLS 256
#define KC 32

// ushort index of (col, koct) base within one 8192-ushort bf16 matrix buffer.
// 128B per col-pair, 8 granules of 16B; granule XOR-swizzled by (col>>2)&7.
__device__ __forceinline__ int swz_idx(int col, int koct){
    return ((col >> 1) << 6) + ((((((col & 1) << 2) | koct)) ^ ((col >> 2) & 7)) << 3);
}

__device__ __forceinline__ int cvt2(float lo, float hi){
    int r;
    asm("v_cvt_pk_bf16_f32 %0, %1, %2" : "=v"(r) : "v"(lo), "v"(hi));
    return r;
}

__device__ __forceinline__ void dma16(const float* g, float* l){
    __builtin_amdgcn_global_load_lds(
        (const __attribute__((address_space(1))) void*)g,
        (__attribute__((address_space(3))) void*)l, 16, 0, 0);
}

__device__ __forceinline__ void vmwait8(){ asm volatile("s_waitcnt vmcnt(8)" ::: "memory"); __builtin_amdgcn_sched_barrier(0); }
__device__ __forceinline__ void vmwait4(){ asm volatile("s_waitcnt vmcnt(4)" ::: "memory"); __builtin_amdgcn_sched_barrier(0); }
__device__ __forceinline__ void vmwait0(){ asm volatile("s_waitcnt vmcnt(0)" ::: "memory"); __builtin_amdgcn_sched_barrier(0); }
__device__ __forceinline__ void lgkm0 (){ asm volatile("s_waitcnt lgkmcnt(0)" ::: "memory"); __builtin_amdgcn_sched_barrier(0); }
__device__ __forceinline__ void barrier(){ __builtin_amdgcn_s_barrier(); __builtin_amdgcn_sched_barrier(0); }

// ---------------------------------------------------------------------------
// K1: streaming GEMM C = c0^T * c1 (bf16 MFMA, fp32 acc) + column sums/sqsums.
// fp32 staged via global_load_lds into a 3-slot half-chunk ring (per-wave
// private regions, no ring barriers); pack converts LDS fp32 -> swizzled bf16.
// ---------------------------------------------------------------------------
__global__ __launch_bounds__(512, 2) void k1_gemm(
        const float* __restrict__ c0, const float* __restrict__ c1,
        float* __restrict__ Pc, float* __restrict__ Ps, int nrows)
{
    const int tid  = threadIdx.x;
    const int w    = tid >> 6;         // wave 0..7
    const int l    = tid & 63;         // lane
    const int mat  = w >> 2;           // staging+compute split
    const int oct4 = w & 3;            // 4-row quad within a 16-row half (DMA)
    const int wr   = w >> 2;           // compute: C row-half (128 rows)
    const int wc   = w & 3;            // compute: C col-quarter (64 cols)
    const int b    = blockIdx.x;
    const int B    = gridDim.x;
    const int nfull = nrows >> 5;      // full 32-row chunks

    __shared__ __align__(16) float ring[3][8192];          // 3 x 32KB half-chunks
    __shared__ __align__(16) unsigned short bbuf[2][8192]; // 32KB bf16 [mat]

    const float* src = mat ? c1 : c0;

    // fragment read offsets (ushort units)
    int idxA[8], idxB[4];
#pragma unroll
    for (int mt = 0; mt < 8; ++mt)
        idxA[mt] = swz_idx(wr*128 + mt*16 + (l & 15), l >> 4);
#pragma unroll
    for (int nt = 0; nt < 4; ++nt)
        idxB[nt] = swz_idx(wc*64 + nt*16 + (l & 15), l >> 4);

    f32x4 acc[8][4];
    const f32x4 zf = {0.f, 0.f, 0.f, 0.f};
#pragma unroll
    for (int i = 0; i < 8; ++i)
#pragma unroll
        for (int j = 0; j < 4; ++j) acc[i][j] = zf;

    float sum[4] = {0.f,0.f,0.f,0.f};
    float sq [4] = {0.f,0.f,0.f,0.f};

    const int T = (b < nfull) ? ((nfull - b - 1) / B + 1) : 0;

    // DMA one half (sequence index j) into ring[slot]: wave region = 4 rows x 256 cols
    auto ISSUE = [&](int j, int slot){
        int cch = b + (j >> 1) * B;
        const float* gb = src + (size_t)(cch*KC + ((j & 1) << 4) + (oct4 << 2)) * KCOLS + (l << 2);
        float* lb = &ring[slot][(w << 10)];
#pragma unroll
        for (int rr = 0; rr < 4; ++rr)
            dma16(gb + rr*KCOLS, lb + (rr << 8));
    };

    // pack my 4-row region of ring[slot] -> bf16 buf; accumulate sums
    auto PACK = [&](int jpar, int slot){
        f32x4 g[4];
        const float* rb = &ring[slot][(w << 10) + (l << 2)];
#pragma unroll
        for (int rr = 0; rr < 4; ++rr) g[rr] = *(const f32x4*)(rb + (rr << 8));
        int kq   = (jpar << 2) | oct4;          // k-quad 0..7
        int koct = kq >> 1;
        char* base = (char*)&bbuf[mat][0] + ((kq & 1) << 3);
#pragma unroll
        for (int cc = 0; cc < 4; ++cc){
            float a0=g[0][cc], a1=g[1][cc], a2=g[2][cc], a3=g[3][cc];
            sum[cc] += (a0+a1)+(a2+a3);
            sq [cc] += (a0*a0+a1*a1)+(a2*a2+a3*a3);
            i32x2 pk; pk.x = cvt2(a0,a1); pk.y = cvt2(a2,a3);
            int col = (l << 2) + cc;
            int off = ((col >> 1) << 7) + (((((cc & 1) << 2) | koct) ^ (l & 7)) << 4);
            *(i32x2*)(base + off) = pk;
        }
    };

    auto MFMA32 = [&](){
        const unsigned short* bufA = &bbuf[0][0];
        const unsigned short* bufB = &bbuf[1][0];
        s16x8 bfr[4];
#pragma unroll
        for (int nt = 0; nt < 4; ++nt) bfr[nt] = *(const s16x8*)&bufB[idxB[nt]];
#pragma unroll
        for (int mt = 0; mt < 8; ++mt){
            s16x8 afr = *(const s16x8*)&bufA[idxA[mt]];
#pragma unroll
            for (int nt = 0; nt < 4; ++nt)
                acc[mt][nt] = __builtin_amdgcn_mfma_f32_16x16x32_bf16(
                                  afr, bfr[nt], acc[mt][nt], 0, 0, 0);
        }
    };

    // ---- prologue: 3 half-batches in flight (4 vmem instrs each) ----
    if (T > 0){
        ISSUE(0, 0);
        ISSUE(1, 1);
        if (T > 1) ISSUE(2, 2);
    }

    for (int t = 0; t < T; ++t){
        const int j0 = 2*t;
        const int s0 = j0 % 3, s1 = (j0 + 1) % 3;
        const bool more = (t < T - 1);

        if (more) vmwait8(); else vmwait4();   // batch j0 landed
        PACK(0, s0);
        if (more) ISSUE(j0 + 3, s0);           // j0+3 exists iff t <= T-2

        if (more) vmwait8(); else vmwait0();   // batch j0+1 landed
        PACK(1, s1);
        if (t < T - 2) ISSUE(j0 + 4, s1);      // j0+4 exists iff t <= T-3

        lgkm0();
        barrier();            // bf16 buf complete for all waves
        MFMA32();
        barrier();            // frag reads done before next pack rewrites buf
    }

    // ---- generic tail (nrows % 32 != 0): register path, guarded ----
    const int rem = nrows - (nfull << 5);
    if (rem > 0 && b == (nfull % B)){
        f32x4 f[8];
        const int rbase = (nfull << 5) + oct4*8;
#pragma unroll
        for (int rr = 0; rr < 8; ++rr){
            int row = rbase + rr;
            f[rr] = (row < nrows) ? *(const f32x4*)(src + (size_t)row*KCOLS + (l << 2)) : zf;
        }
#pragma unroll
        for (int cc = 0; cc < 4; ++cc){
            float v0=f[0][cc], v1=f[1][cc], v2=f[2][cc], v3=f[3][cc];
            float v4=f[4][cc], v5=f[5][cc], v6=f[6][cc], v7=f[7][cc];
            sum[cc] += ((v0+v1)+(v2+v3)) + ((v4+v5)+(v6+v7));
            sq [cc] += ((v0*v0+v1*v1)+(v2*v2+v3*v3)) + ((v4*v4+v5*v5)+(v6*v6+v7*v7));
            i32x4 pk;
            pk.x = cvt2(v0,v1); pk.y = cvt2(v2,v3);
            pk.z = cvt2(v4,v5); pk.w = cvt2(v6,v7);
            int col = (l << 2) + cc;
            int offu = swz_idx(col, oct4);
            *(i32x4*)&bbuf[mat][offu] = pk;
        }
        lgkm0();
        barrier();
        MFMA32();
    }

    // ---- write 256x256 fp32 C partial ----
    float* Pb = Pc + (size_t)b * 65536;
#pragma unroll
    for (int mt = 0; mt < 8; ++mt)
#pragma unroll
        for (int nt = 0; nt < 4; ++nt)
#pragma unroll
            for (int r = 0; r < 4; ++r){
                int row = wr*128 + mt*16 + (l >> 4)*4 + r;  // C/D: row=(l>>4)*4+reg
                int cl  = wc*64  + nt*16 + (l & 15);        //      col=l&15
                Pb[row*256 + cl] = acc[mt][nt][r];
            }

    // ---- reduce per-block column sums (reuse ring LDS; all DMA drained) ----
    float* sredp = &ring[0][0];          // [2][4][256]
    float* qredp = sredp + 2048;
    __syncthreads();
#pragma unroll
    for (int cc = 0; cc < 4; ++cc){
        sredp[(mat*4 + oct4)*256 + (l << 2) + cc] = sum[cc];
        qredp[(mat*4 + oct4)*256 + (l << 2) + cc] = sq[cc];
    }
    __syncthreads();
    {
        int m2 = tid >> 8, cl = tid & 255;
        float s = sredp[(m2*4+0)*256+cl] + sredp[(m2*4+1)*256+cl]
                + sredp[(m2*4+2)*256+cl] + sredp[(m2*4+3)*256+cl];
        float q = qredp[(m2*4+0)*256+cl] + qredp[(m2*4+1)*256+cl]
                + qredp[(m2*4+2)*256+cl] + qredp[(m2*4+3)*256+cl];
        Ps[(size_t)b*1024 + m2*512 + cl]       = s;
        Ps[(size_t)b*1024 + m2*512 + 256 + cl] = q;
    }
}

// ---------------------------------------------------------------------------
// K2: reduce per-block sum partials -> finals[1024] = {s0,q0,s1,q1} (fp64 acc)
// ---------------------------------------------------------------------------
__global__ __launch_bounds__(256) void k2_sum(const float* __restrict__ Ps,
                                              float* __restrict__ fin, int B)
{
    int tid = threadIdx.x;
    int u   = blockIdx.x*64 + (tid & 63);
    int sub = tid >> 6;
    double a = 0.0;
    for (int b = sub; b < B; b += 4) a += Ps[(size_t)b*1024 + u];
    __shared__ double sc2[4][64];
    sc2[sub][tid & 63] = a;
    __syncthreads();
    if (sub == 0)
        fin[u] = (float)(sc2[0][tid] + sc2[1][tid] + sc2[2][tid] + sc2[3][tid]);
}

// ---------------------------------------------------------------------------
// K3: per C-row j: reduce C partials, cosine, row softmax, t_j = log(diag+eps)
// ---------------------------------------------------------------------------
__global__ __launch_bounds__(512) void k3_rows(const float* __restrict__ Pc,
        const float* __restrict__ fin, float* __restrict__ tout, int B)
{
    const int j   = blockIdx.x;
    const int tid = threadIdx.x;
    const int l   = tid & 255;
    const int h   = tid >> 8;

    __shared__ float part[2][256];
    __shared__ float cosS[256];
    __shared__ float wred[8];

    double a = 0.0;
    int b0 = h ? (B >> 1) : 0;
    int b1 = h ? B        : (B >> 1);
    for (int b = b0; b < b1; ++b)
        a += Pc[(size_t)b*65536 + j*256 + l];
    part[h][l] = (float)a;
    __syncthreads();

    if (h == 0){
        float Cjl = part[0][l] + part[1][l];
        float d0 = fin[j]       + 1e-8f, q0 = fin[256 + j];
        float d1 = fin[512 + l] + 1e-8f, q1 = fin[768 + l];
        float rs0 = rsqrtf(fmaxf(q0 / (d0*d0), 1e-12f));
        float rs1 = rsqrtf(fmaxf(q1 / (d1*d1), 1e-12f));
        cosS[l] = Cjl * (rs0 / d0) * (rs1 / d1);
    }
    __syncthreads();

    float v  = (tid < 256) ? cosS[tid] : -3.0e38f;
    float mx = v;
#pragma unroll
    for (int o = 32; o >= 1; o >>= 1) mx = fmaxf(mx, __shfl_xor(mx, o));
    if ((tid & 63) == 0) wred[tid >> 6] = mx;
    __syncthreads();
    mx = wred[0];
#pragma unroll
    for (int i = 1; i < 8; ++i) mx = fmaxf(mx, wred[i]);
    __syncthreads();

    float e = (tid < 256) ? expf(cosS[tid] - mx) : 0.0f;
    float s = e;
#pragma unroll
    for (int o = 32; o >= 1; o >>= 1) s += __shfl_xor(s, o);
    if ((tid & 63) == 0) wred[tid >> 6] = s;
    __syncthreads();
    float S = ((wred[0]+wred[1])+(wred[2]+wred[3])) + ((wred[4]+wred[5])+(wred[6]+wred[7]));

    if (tid == j){
        float dg = expf(cosS[j] - mx) / S;
        tout[j] = logf(dg + 1e-8f);
    }
}

// ---------------------------------------------------------------------------
// K4: finalize — cls loss + fp64 entropy terms -> d_out[0], d_out[1]
// ---------------------------------------------------------------------------
__global__ __launch_bounds__(256) void k4_fin(const float* __restrict__ fin,
        const float* __restrict__ tout, const int* __restrict__ kptr,
        float* __restrict__ out)
{
    const int tid = threadIdx.x;  // 256 threads
    __shared__ double sc[4];
    auto bsum = [&](double v) -> double {
#pragma unroll
        for (int o = 32; o >= 1; o >>= 1) v += __shfl_xor(v, o);
        if ((tid & 63) == 0) sc[tid >> 6] = v;
        __syncthreads();
        double r = sc[0] + sc[1] + sc[2] + sc[3];
        __syncthreads();
        return r;
    };

    double s0 = fin[tid], s1 = fin[512 + tid];
    double S0 = bsum(s0), S1 = bsum(s1);
    double p0 = s0 / S0, p1 = s1 / S1;
    double T0 = bsum(p0 * log(p0));
    double T1 = bsum(p1 * log(p1));
    double Tc = bsum((double)tout[tid]);

    if (tid == 0){
        double lk = log((double)(*kptr));
        out[0] = (float)(-(Tc / 256.0));
        out[1] = (float)((T0 + lk) + (T1 + lk));
    }
}

extern "C" void kernel_launch(void* const* d_in, const int* in_sizes, int n_in,
                              void* d_out, int out_size, void* d_ws, size_t ws_size,
                              hipStream_t stream)
{
    const float* c0  = (const float*)d_in[0];
    const float* c1  = (const float*)d_in[1];
    const int*  kptr = (const int*)d_in[2];
    float* out = (float*)d_out;
    int nrows = in_sizes[0] / KCOLS;

    // B=250: 6250 chunks / 250 = exactly 25 iterations per block
    int B = 250;
    size_t need = ((size_t)B*66560 + 1280) * sizeof(float);
    if (need > ws_size){
        long cap = (long)(ws_size / sizeof(float)) - 1280;
        long bb  = cap / 66560;
        B = (int)(bb < 1 ? 1 : (bb > 250 ? 250 : bb));
    }
    float* Pc  = (float*)d_ws;                 // B * 65536
    float* Ps  = Pc + (size_t)B * 65536;       // B * 1024
    float* fin = Ps + (size_t)B * 1024;        // 1024
    float* tv  = fin + 1024;                   // 256

    hipLaunchKernelGGL(k1_gemm, dim3(B),   dim3(512), 0, stream, c0, c1, Pc, Ps, nrows);
    hipLaunchKernelGGL(k2_sum,  dim3(16),  dim3(256), 0, stream, Ps, fin, B);
    hipLaunchKernelGGL(k3_rows, dim3(256), dim3(512), 0, stream, Pc, fin, tv, B);
    hipLaunchKernelGGL(k4_fin,  dim3(1),   dim3(256), 0, stream, fin, tv, kptr, out);
}